// Round 8
// baseline (159.283 us; speedup 1.0000x reference)
//
#include <hip/hip_runtime.h>

// RobustAttention: blockwise (w=15) causal cosFormer linear attention.
// scores[l,j] = cos(th_l - th_j) * <relu(q_l), relu(k_j)>, j<=l
// out[l] = sum_j scores[l,j] * relu(v_j) / max(sum_j scores[l,j], 1e-6)
//
// R11: occupancy is triple-falsified (R3 2blk / R6 4blk / R10 10waves all
// ~74-79 us). Pipe accounting per CU: VALU ~32us, LDS ~27us, HBM ~31us —
// measured 74 ~ the SUM: each wave serializes load-stall -> compute ->
// load-stall with no self-overlap. Fix: T3 minimum 2-phase pipeline.
//  - k double-buffered in LDS via global_load_lds (fire-and-forget, no
//    staging regs, no ds_writes). NEXT batch's 16 glls issue AFTER this
//    batch's q/v loads (vmcnt FIFO: q/v are OLDER, so consuming them
//    leaves the glls in flight) and are waited only at the NEXT
//    iteration's first slab touch -> k HBM latency hides under ~4000cy
//    of dots+phase2.
//  - gll needs raw data + linear dest: relu(k) becomes an in-place LDS
//    pass (15 RMW/thread); tile slots padded to 258 float4 so the 4
//    broadcast groups sit on banks 0/8/16/24 (conflict-free).
//  - Single-wave WGs, no barriers (compiler's waitcnt pass orders all
//    intra-wave LDS hazards). ITERS=4 batches/WG, 1280 WGs.
//  - __launch_bounds__(64,1): LDS (33KB -> 4-5 WGs/CU) is the binding
//    occupancy cap anyway; give the allocator the full file so the
//    q/v in-flight registers (~160 live) never spill.
// Red line: WRITE_SIZE must stay 76,800 KB.

namespace {

constexpr int W        = 15;             // block_size (rows per tile)
constexpr int CH       = 16;             // float4 per row (D=64)
constexpr int TILE4    = W * CH;         // 240 float4 per tile
constexpr int TPW      = 4;              // tiles per wave/batch
constexpr int NTHREADS = 64;             // one wave
constexpr int ITERS    = 4;              // batches per workgroup
constexpr int SLOT4    = 258;            // padded tile slot (4128 B): banks 0/8/16/24
constexpr int BUF4     = TPW * SLOT4;    // 1032 float4 per buffer
constexpr int BATCH4   = TPW * TILE4;    // 960 valid float4 per batch

typedef float f32x4_n __attribute__((ext_vector_type(4)));

__device__ __forceinline__ float4 relu4(float4 a) {
    return make_float4(fmaxf(a.x, 0.f), fmaxf(a.y, 0.f),
                       fmaxf(a.z, 0.f), fmaxf(a.w, 0.f));
}

__device__ __forceinline__ void gll16(const float4* g, float4* l) {
    __builtin_amdgcn_global_load_lds(
        (const __attribute__((address_space(1))) void*)g,
        (__attribute__((address_space(3))) void*)l, 16, 0, 0);
}

__global__ __launch_bounds__(NTHREADS, 1)
void robust_attn_kernel(const float4* __restrict__ q4,
                        const float4* __restrict__ k4,
                        const float4* __restrict__ v4,
                        float4* __restrict__ o4,
                        int nblocks)
{
    __shared__ float4 slab[2 * BUF4];    // 2 x 16,512 B = 33,024 B

    const int tid      = threadIdx.x;    // == lane
    const int lane     = tid & 15;       // row l (ph1) / d-chunk (ph2)
    const int t        = tid >> 4;       // tile within batch (0..3)
    const int nbatches = (nblocks + TPW - 1) / TPW;
    const int b0       = (int)blockIdx.x * ITERS;
    const int limit4   = nblocks * TILE4;

    // ---- issue 16 global_load_lds for raw k of `batch` into slab half ----
    auto stage = [&](int batch, float4* sN) {
        if (batch >= nbatches) return;
        const int gbase = batch * BATCH4;
#pragma unroll
        for (int tt = 0; tt < TPW; ++tt) {
#pragma unroll
            for (int c = 0; c < 4; ++c) {
                const int pos  = c * 64 + tid;        // 0..255 in tile slot
                const int gidx = gbase + tt * TILE4 + pos;
                if (pos < TILE4 && gidx < limit4)     // exec-masked gll
                    gll16(k4 + gidx, sN + tt * SLOT4 + pos);
            }
        }
    };

    // ---- one batch: prefetch-next + compute-current ----
    auto body = [&](int batch, float4* sC, float4* sN) {
        if (batch >= nbatches) return;
        const int  g      = batch * TPW + t;
        const bool active = (g < nblocks);
        const bool ph1    = active && (lane < W);

        // (a) issue q row loads (oldest vmem of this iteration)
        float4 qraw[CH];
        const float4* __restrict__ qp = q4 + (size_t)g * TILE4 + lane * CH;
#pragma unroll
        for (int c = 0; c < CH; ++c)
            qraw[c] = active ? qp[c] : make_float4(0.f, 0.f, 0.f, 0.f);

        // (b) issue v loads
        float4 vraw[W];
        const float4* __restrict__ vp = v4 + (size_t)g * TILE4 + lane;
#pragma unroll
        for (int j = 0; j < W; ++j)
            vraw[j] = active ? vp[j * CH] : make_float4(0.f, 0.f, 0.f, 0.f);

        // (c) in-place relu pass on current slab — first touch of sC:
        //     auto vmcnt wait retires the (oldest) glls of the PREV iter.
#pragma unroll
        for (int r = 0; r < BATCH4 / NTHREADS; ++r) {   // 15 RMW/thread
            const int idx = tid + r * NTHREADS;
            const int tt  = idx / TILE4;
            const int pos = idx - tt * TILE4;
            float4* p = sC + tt * SLOT4 + pos;
            *p = relu4(*p);
        }

        // (d) issue NEXT batch's k prefetch — newest vmem: stays in flight
        //     across dots+phase2 until the next iteration's (c).
        stage(batch + 1, sN);

        // (e) dots: s[j] = <relu(q_l), relu(k_j)> (k broadcast from slab)
        float s[W];
#pragma unroll
        for (int j = 0; j < W; ++j) s[j] = 0.f;

        if (ph1) {
            float4 qr[CH];
#pragma unroll
            for (int c = 0; c < CH; ++c) qr[c] = relu4(qraw[c]);

            const float4* __restrict__ kl = sC + t * SLOT4;
#pragma unroll
            for (int j = 0; j < W; ++j) {
                float acc = 0.f;
#pragma unroll
                for (int c = 0; c < CH; ++c) {
                    const float4 kk = kl[j * CH + c];
                    acc = fmaf(qr[c].x, kk.x, acc);
                    acc = fmaf(qr[c].y, kk.y, acc);
                    acc = fmaf(qr[c].z, kk.z, acc);
                    acc = fmaf(qr[c].w, kk.w, acc);
                }
                s[j] = acc;
            }

            // (f) causal cos-weight + normalize
            const int   l    = lane;
            const float step = 1.57079632679489662f / (float)W;  // (pi/2)/15
            float denom = 0.f;
#pragma unroll
            for (int j = 0; j < W; ++j) {
                float wc = __cosf(step * (float)(l - j));
                float tv = (j <= l) ? s[j] * wc : 0.f;
                s[j] = tv;
                denom += tv;
            }
            const float inv = 1.f / fmaxf(denom, 1e-6f);
#pragma unroll
            for (int j = 0; j < W; ++j) s[j] *= inv;
        }

        // (g) phase 2: out = S @ relu(v); weights via wave shuffle
        if (active) {
            float4* __restrict__ op = o4 + (size_t)g * TILE4 + lane;
            const int tbase = tid & 48;
#pragma unroll
            for (int l = 0; l < W; ++l) {
                float ax = 0.f, ay = 0.f, az = 0.f, aw = 0.f;
#pragma unroll
                for (int j = 0; j <= l; ++j) {     // causal
                    const float w = __shfl(s[j], tbase + l, 64);
                    const float4 vj = relu4(vraw[j]);
                    ax = fmaf(w, vj.x, ax);
                    ay = fmaf(w, vj.y, ay);
                    az = fmaf(w, vj.z, az);
                    aw = fmaf(w, vj.w, aw);
                }
                // (h) nontemporal store: don't evict L3-resident inputs
                f32x4_n val = {ax, ay, az, aw};
                __builtin_nontemporal_store(val, (f32x4_n*)(op + l * CH));
            }
        }
    };

    // ---- prologue + 2-phase pipelined loop (static buffer selection) ------
    float4* slabA = &slab[0];
    float4* slabB = &slab[BUF4];

    stage(b0, slabA);
#pragma unroll
    for (int i = 0; i < ITERS; i += 2) {
        body(b0 + i,     slabA, slabB);
        body(b0 + i + 1, slabB, slabA);
    }
}

}  // namespace

extern "C" void kernel_launch(void* const* d_in, const int* in_sizes, int n_in,
                              void* d_out, int out_size, void* d_ws, size_t ws_size,
                              hipStream_t stream) {
    const float4* q = (const float4*)d_in[0];
    const float4* k = (const float4*)d_in[1];
    const float4* v = (const float4*)d_in[2];
    float4* out = (float4*)d_out;

    const int total    = in_sizes[0];            // B*H*L*D
    const int nblocks  = total / (W * CH * 4);   // 20480 for the bench shape
    const int nbatches = (nblocks + TPW - 1) / TPW;
    const int wgs      = (nbatches + ITERS - 1) / ITERS;

    robust_attn_kernel<<<wgs, NTHREADS, 0, stream>>>(q, k, v, out, nblocks);
}

// Round 9
// 152.536 us; speedup vs baseline: 1.0442x; 1.0442x over previous
//
#include <hip/hip_runtime.h>

// RobustAttention: blockwise (w=15) causal cosFormer linear attention.
// scores[l,j] = cos(th_l - th_j) * <relu(q_l), relu(k_j)>, j<=l
// out[l] = sum_j scores[l,j] * relu(v_j) / max(sum_j scores[l,j], 1e-6)
//
// R12: R11's 2-phase pipeline was clean (no spill) but collapsed residency
// (33 KB LDS x 1-wave WGs = 4 waves/CU = 1/SIMD -> 7.7% occupancy, 159us).
// Mechanism tally: residency alone (R3/R6/R10) flat ~74us; pipeline alone
// at 1 wave/SIMD = 159us. R12 combines them:
//  - SINGLE 16,512 B k-slab (not double-buffered) -> 9 WGs/CU resident.
//  - k prefetch via REGISTERS (T14 async-split): issue next-batch k loads
//    before this batch's compute, ds_write them after phase 2. The in-order
//    per-wave DS pipe makes the WAR (dots read cur k, then writes of next k)
//    safe; one cheap single-wave __syncthreads seals the iteration.
//  - Load-issue order q -> v -> k_next == consumption order, so counted
//    vmcnt waits (FIFO) leave younger loads in flight: q latency hides
//    under nothing (first), v under dots, k_next under dots+phase2.
//  - q back to direct scattered loads (q-through-LDS was worth only ~3%,
//    R8 vs R6; not worth a second buffer / lower residency here).
//  - Tile slots padded to 258 float4: group t base = t*4128 B -> banks
//    0/8/16/24, broadcast dot-reads conflict-free; ds_writes 2-way (free).
//  - __launch_bounds__(64,2): VGPR cap 256 > ~200 live peak.
//  - ITERS=2 -> 2560 WGs (> 256 CU x 9 resident; tail-friendly).
//  - NT output stores kept.
// Red line: WRITE_SIZE must stay 76,800 KB (spill detector).

namespace {

constexpr int W        = 15;             // block_size (rows per tile)
constexpr int CH       = 16;             // float4 per row (D=64)
constexpr int TILE4    = W * CH;         // 240 float4 per tile
constexpr int TPW      = 4;              // tiles per wave/batch
constexpr int NTHREADS = 64;             // one wave
constexpr int ITERS    = 2;              // batches per workgroup
constexpr int SLOT4    = 258;            // padded tile slot: banks 0/8/16/24
constexpr int BUF4     = TPW * SLOT4;    // 1032 float4 = 16,512 B

typedef float f32x4_n __attribute__((ext_vector_type(4)));

__device__ __forceinline__ float4 relu4(float4 a) {
    return make_float4(fmaxf(a.x, 0.f), fmaxf(a.y, 0.f),
                       fmaxf(a.z, 0.f), fmaxf(a.w, 0.f));
}

__global__ __launch_bounds__(NTHREADS, 2)
void robust_attn_kernel(const float4* __restrict__ q4,
                        const float4* __restrict__ k4,
                        const float4* __restrict__ v4,
                        float4* __restrict__ o4,
                        int nblocks)
{
    __shared__ float4 slab[BUF4];        // 16,512 B — single k buffer

    const int tid      = threadIdx.x;    // == lane (one wave)
    const int lane     = tid & 15;       // row l (ph1) / d-chunk (ph2)
    const int t        = tid >> 4;       // tile within batch (0..3)
    const int nbatches = (nblocks + TPW - 1) / TPW;
    const int b0       = (int)blockIdx.x * ITERS;

    // ---------- prologue: stage k for batch b0 through registers ----------
    if (b0 < nbatches) {
        const int  g      = b0 * TPW + t;
        const bool active = (g < nblocks);
        const float4* __restrict__ kp = k4 + (size_t)g * TILE4 + lane;
        float4 kw[W];
#pragma unroll
        for (int j = 0; j < W; ++j)
            kw[j] = active ? kp[j * CH] : make_float4(0.f, 0.f, 0.f, 0.f);
#pragma unroll
        for (int j = 0; j < W; ++j)
            slab[t * SLOT4 + j * CH + lane] = relu4(kw[j]);
    }
    __syncthreads();   // single-wave WG: lowers to a cheap lgkm drain

#pragma unroll
    for (int i = 0; i < ITERS; ++i) {
        const int batch = b0 + i;
        if (batch < nbatches) {
            const int  g      = batch * TPW + t;
            const bool active = (g < nblocks);
            const bool ph1    = active && (lane < W);

            // (1) q: direct per-lane row loads (oldest vmem this iter)
            float4 qr[CH];
            const float4* __restrict__ qp =
                q4 + (size_t)g * TILE4 + lane * CH;
#pragma unroll
            for (int c = 0; c < CH; ++c)
                qr[c] = ph1 ? relu4(qp[c]) : make_float4(0.f, 0.f, 0.f, 0.f);

            // (2) v: coalesced loads, consumed in phase 2
            float4 vv[W];
            const float4* __restrict__ vp =
                v4 + (size_t)g * TILE4 + lane;
#pragma unroll
            for (int j = 0; j < W; ++j)
                vv[j] = active ? relu4(vp[j * CH])
                               : make_float4(0.f, 0.f, 0.f, 0.f);

            // (3) k prefetch for NEXT batch into registers (youngest vmem:
            //     stays in flight across dots + phase 2, consumed at (8))
            const bool pn = (i + 1 < ITERS) && (batch + 1 < nbatches);
            const int  gn = (batch + 1) * TPW + t;
            const bool an = pn && (gn < nblocks);
            float4 kn[W];
            const float4* __restrict__ knp =
                k4 + (size_t)gn * TILE4 + lane;
#pragma unroll
            for (int j = 0; j < W; ++j)
                kn[j] = an ? knp[j * CH] : make_float4(0.f, 0.f, 0.f, 0.f);

            // (4) dots: s[j] = <relu(q_l), relu(k_j)>, k broadcast from slab
            float s[W];
#pragma unroll
            for (int j = 0; j < W; ++j) s[j] = 0.f;

            if (ph1) {
                const float4* __restrict__ kl = &slab[t * SLOT4];
#pragma unroll
                for (int j = 0; j < W; ++j) {
                    float acc = 0.f;
#pragma unroll
                    for (int c = 0; c < CH; ++c) {
                        const float4 kk = kl[j * CH + c];
                        acc = fmaf(qr[c].x, kk.x, acc);
                        acc = fmaf(qr[c].y, kk.y, acc);
                        acc = fmaf(qr[c].z, kk.z, acc);
                        acc = fmaf(qr[c].w, kk.w, acc);
                    }
                    s[j] = acc;
                }

                // (5) causal cos-weight + normalize
                const int   l    = lane;
                const float step = 1.57079632679489662f / (float)W;
                float denom = 0.f;
#pragma unroll
                for (int j = 0; j < W; ++j) {
                    float wc = __cosf(step * (float)(l - j));
                    float tv = (j <= l) ? s[j] * wc : 0.f;
                    s[j] = tv;
                    denom += tv;
                }
                const float inv = 1.f / fmaxf(denom, 1e-6f);
#pragma unroll
                for (int j = 0; j < W; ++j) s[j] *= inv;
            }

            // (6)+(7) phase 2: out = S @ relu(v), weights via wave shuffle
            if (active) {
                float4* __restrict__ op = o4 + (size_t)g * TILE4 + lane;
                const int tbase = tid & 48;
#pragma unroll
                for (int l = 0; l < W; ++l) {
                    float ax = 0.f, ay = 0.f, az = 0.f, aw = 0.f;
#pragma unroll
                    for (int j = 0; j <= l; ++j) {     // causal
                        const float w = __shfl(s[j], tbase + l, 64);
                        ax = fmaf(w, vv[j].x, ax);
                        ay = fmaf(w, vv[j].y, ay);
                        az = fmaf(w, vv[j].z, az);
                        aw = fmaf(w, vv[j].w, aw);
                    }
                    // nontemporal: don't evict L3-resident inputs
                    f32x4_n val = {ax, ay, az, aw};
                    __builtin_nontemporal_store(val, (f32x4_n*)(op + l * CH));
                }
            }

            // (8) write next-batch k into the slab. Safe WAR: per-wave DS
            //     pipe is in-order (reads at (4) precede these writes) and
            //     the compiler preserves slab aliasing order.
            if (pn) {
#pragma unroll
                for (int j = 0; j < W; ++j)
                    slab[t * SLOT4 + j * CH + lane] = relu4(kn[j]);
            }
        }
        __syncthreads();   // seal iteration (trivial for single-wave WG)
    }
}

}  // namespace

extern "C" void kernel_launch(void* const* d_in, const int* in_sizes, int n_in,
                              void* d_out, int out_size, void* d_ws, size_t ws_size,
                              hipStream_t stream) {
    const float4* q = (const float4*)d_in[0];
    const float4* k = (const float4*)d_in[1];
    const float4* v = (const float4*)d_in[2];
    float4* out = (float4*)d_out;

    const int total    = in_sizes[0];            // B*H*L*D
    const int nblocks  = total / (W * CH * 4);   // 20480 for the bench shape
    const int nbatches = (nblocks + TPW - 1) / TPW;
    const int wgs      = (nbatches + ITERS - 1) / ITERS;

    robust_attn_kernel<<<wgs, NTHREADS, 0, stream>>>(q, k, v, out, nblocks);
}

// Round 10
// 79.943 us; speedup vs baseline: 1.9925x; 1.9081x over previous
//
#include <hip/hip_runtime.h>

// RobustAttention: blockwise (w=15) causal cosFormer linear attention.
// scores[l,j] = cos(th_l - th_j) * <relu(q_l), relu(k_j)>, j<=l
// out[l] = sum_j scores[l,j] * relu(v_j) / max(sum_j scores[l,j], 1e-6)
//
// R13: register-budget reality (R7/R11/R12): allocator tops out ~148 VGPR
// and spills rather than exceed it, regardless of __launch_bounds__ cap.
// => no cross-iteration prefetch arrays. Attack the serial chain instead:
// R8 has 3 barriers + 2 full vmem drains purely because q and k time-share
// one LDS buffer. This version:
//  - k-only LDS buffer (66,048 B, slot-padded 258 f4 -> wave's 4 broadcast
//    groups on banks 0/8/16/24). 2 WGs/CU = 8 waves (R8 residency).
//  - q prefetched into REGISTERS pre-barrier (raw; relu at consume): its
//    ~700cy scattered-load latency hides under the k-stage drain. R8 proved
//    q-through-LDS is only worth ~3%; hiding the latency gets most of that
//    without the 2 extra barriers.
//  - ONE __syncthreads total (was 3). One vmem drain (was 2).
//  - v loads stay at phase-2 start (R8's proven-clean liveness: vv never
//    overlaps qr+staging peak). Peak live ~130-140 < 148 proven envelope.
//  - NT output stores kept.
// Red line: WRITE_SIZE must stay 76,800 KB (spill detector).

namespace {

constexpr int W        = 15;             // block_size (rows per tile)
constexpr int CH       = 16;             // float4 per row (D=64)
constexpr int TILE4    = W * CH;         // 240 float4 per tile
constexpr int TPG      = 16;             // tiles per workgroup
constexpr int NTHREADS = 256;
constexpr int SLOT4    = 258;            // padded tile slot: group banks 0/8/16/24
constexpr int LDS4     = TPG * SLOT4;    // 4128 float4 = 66,048 B

typedef float f32x4_n __attribute__((ext_vector_type(4)));

__device__ __forceinline__ float4 relu4(float4 a) {
    return make_float4(fmaxf(a.x, 0.f), fmaxf(a.y, 0.f),
                       fmaxf(a.z, 0.f), fmaxf(a.w, 0.f));
}

__global__ __launch_bounds__(NTHREADS, 2)
void robust_attn_kernel(const float4* __restrict__ q4,
                        const float4* __restrict__ k4,
                        const float4* __restrict__ v4,
                        float4* __restrict__ o4,
                        int nblocks)
{
    __shared__ float4 k_lds[LDS4];       // 66,048 B

    const int tid  = threadIdx.x;
    const int lane = tid & 15;           // row l (ph1) / d-chunk (ph2)
    const int t    = tid >> 4;           // tile within WG
    const int g0   = blockIdx.x * TPG;
    const int g    = g0 + t;
    const bool active = (g < nblocks);
    const bool ph1    = active && (lane < W);

    // ---- (1) stage relu(k) into LDS: coalesced loads, padded slots --------
    {
        const size_t base  = (size_t)g0 * TILE4;
        const bool   full  = (g0 + TPG <= nblocks);
        const int    limit = nblocks * TILE4 - (int)base;
#pragma unroll
        for (int r = 0; r < (TPG * TILE4) / NTHREADS; ++r) {   // 15 iters
            const int idx = tid + r * NTHREADS;
            float4 kk = make_float4(0.f, 0.f, 0.f, 0.f);
            if (full || idx < limit) kk = k4[base + idx];
            const int tt  = idx / TILE4;
            const int pos = idx - tt * TILE4;
            k_lds[tt * SLOT4 + pos] = relu4(kk);
        }
    }

    // ---- (2) prefetch q rows into registers (raw) — latency hides under
    //          the k-stage drain at the barrier below ------------------------
    float4 qr[CH];
    {
        const float4* __restrict__ qp = q4 + (size_t)g * TILE4 + lane * CH;
#pragma unroll
        for (int c = 0; c < CH; ++c)
            qr[c] = ph1 ? qp[c] : make_float4(0.f, 0.f, 0.f, 0.f);
    }

    __syncthreads();   // the ONLY barrier: drains k-stage (and q loads)

    // ---- (3) phase 1: dots (k broadcast from LDS), cos-weight, normalize --
    float s[W];
#pragma unroll
    for (int j = 0; j < W; ++j) s[j] = 0.f;

    if (ph1) {
#pragma unroll
        for (int c = 0; c < CH; ++c) qr[c] = relu4(qr[c]);

        const float4* __restrict__ kl = &k_lds[t * SLOT4];
#pragma unroll
        for (int j = 0; j < W; ++j) {
            float acc = 0.f;
#pragma unroll
            for (int c = 0; c < CH; ++c) {
                const float4 kk = kl[j * CH + c];
                acc = fmaf(qr[c].x, kk.x, acc);
                acc = fmaf(qr[c].y, kk.y, acc);
                acc = fmaf(qr[c].z, kk.z, acc);
                acc = fmaf(qr[c].w, kk.w, acc);
            }
            s[j] = acc;
        }

        const int   l    = lane;
        const float step = 1.57079632679489662f / (float)W;  // (pi/2)/15
        float denom = 0.f;
#pragma unroll
        for (int j = 0; j < W; ++j) {
            float wc = __cosf(step * (float)(l - j));
            float tv = (j <= l) ? s[j] * wc : 0.f;
            s[j] = tv;
            denom += tv;
        }
        const float inv = 1.f / fmaxf(denom, 1e-6f);
#pragma unroll
        for (int j = 0; j < W; ++j) s[j] *= inv;
    }

    // ---- (4) phase 2: out = S @ relu(v); weights via wave shuffle ---------
    if (active) {
        const float4* __restrict__ vp = v4 + (size_t)g * TILE4 + lane;
        float4* __restrict__ op       = o4 + (size_t)g * TILE4 + lane;

        float4 vv[W];
#pragma unroll
        for (int j = 0; j < W; ++j) vv[j] = relu4(vp[j * CH]);

        const int tbase = tid & 48;   // tile base lane within the wave
#pragma unroll
        for (int l = 0; l < W; ++l) {
            float ax = 0.f, ay = 0.f, az = 0.f, aw = 0.f;
#pragma unroll
            for (int j = 0; j <= l; ++j) {     // causal
                const float w = __shfl(s[j], tbase + l, 64);
                ax = fmaf(w, vv[j].x, ax);
                ay = fmaf(w, vv[j].y, ay);
                az = fmaf(w, vv[j].z, az);
                aw = fmaf(w, vv[j].w, aw);
            }
            // nontemporal: output stream must not evict L3-resident inputs
            f32x4_n val = {ax, ay, az, aw};
            __builtin_nontemporal_store(val, (f32x4_n*)(op + l * CH));
        }
    }
}

}  // namespace

extern "C" void kernel_launch(void* const* d_in, const int* in_sizes, int n_in,
                              void* d_out, int out_size, void* d_ws, size_t ws_size,
                              hipStream_t stream) {
    const float4* q = (const float4*)d_in[0];
    const float4* k = (const float4*)d_in[1];
    const float4* v = (const float4*)d_in[2];
    float4* out = (float4*)d_out;

    const int total   = in_sizes[0];           // B*H*L*D
    const int nblocks = total / (W * CH * 4);  // 20480 for the bench shape
    const int wgs     = (nblocks + TPG - 1) / TPG;

    robust_attn_kernel<<<wgs, NTHREADS, 0, stream>>>(q, k, v, out, nblocks);
}